// Round 12
// baseline (28.137 us; speedup 1.0000x reference)
//
#include <hip/hip_runtime.h>
#include <hip/hip_bf16.h>

typedef float f4 __attribute__((ext_vector_type(4)));
typedef float f32x4 __attribute__((ext_vector_type(4)));
typedef short s16x8 __attribute__((ext_vector_type(8)));

// MFMA GEMM, no LDS in main loop, no cross-lane reduction (R11 structure).
// Block = 4 waves = 32 tokens; wave w owns k-quarter [w*256,+256).
// A-frag loaded DIRECTLY from global: lane l = token (l&15), 8 contiguous
// k-floats at (l>>4)*8. B-frag (weights, padded 9->16 experts) bf16 in 32
// VGPRs. R12 changes vs R11:
//  (1) ring depth 2 -> 3-ahead (4 slots): 12 KB/wave in flight, data age
//      at use ~450+ cyc >= warm-L3 latency (R10 profile showed 850 GB/s
//      cold => latency-bound, not BW-bound).
//  (2) pack8 via v_cvt_pk_bf16_f32 (__float22bfloat162_rn): 4 instrs vs
//      ~30 manual-RNE => halves per-step VALU, shortens load->mfma chain.
// Epilogue: 8KB LDS combine of 4 k-quarter partials + 32 parallel softmaxes.

#define TPB 32   // tokens per block

__device__ __forceinline__ s16x8 pack8(f4 a, f4 b) {
  union { s16x8 v; __hip_bfloat162 h[4]; } u;
  u.h[0] = __float22bfloat162_rn({a.x, a.y});
  u.h[1] = __float22bfloat162_rn({a.z, a.w});
  u.h[2] = __float22bfloat162_rn({b.x, b.y});
  u.h[3] = __float22bfloat162_rn({b.z, b.w});
  return u.v;
}

__global__ __launch_bounds__(256)
void moa_mfma3(const float* __restrict__ tok,
               const float* __restrict__ Wq,
               const float* __restrict__ Wk,
               const float* __restrict__ Wv,
               float* __restrict__ out) {
  __shared__ float clds[4 * 512];                 // 8 KB: [wave][32 tok][16 col]
  const int tid  = threadIdx.x;
  const int wv   = tid >> 6;
  const int lane = tid & 63;
  const int n    = lane & 15;                     // A: token row / B: expert col
  const int kg   = lane >> 4;                     // k-group of 8
  const int kq   = wv * 256;                      // wave's k-quarter

  // ---- B-frags: this wave's weight quarter, bf16, 8 steps ----
  const float* wrow = (n < 3) ? (Wq + n * 1024)
                    : (n < 6) ? (Wk + (n - 3) * 1024)
                    : (n < 9) ? (Wv + (n - 6) * 1024) : Wq;
  const bool wvalid = (n < 9);
  s16x8 bfrag[8];
#pragma unroll
  for (int s = 0; s < 8; ++s) {
    const float* p = wrow + kq + s * 32 + kg * 8;
    f4 wa = wvalid ? *(const f4*)p       : (f4)0.0f;
    f4 wb = wvalid ? *(const f4*)(p + 4) : (f4)0.0f;
    bfrag[s] = pack8(wa, wb);
  }

  // ---- A pointers: two 16-token tiles per wave ----
  const int T0 = blockIdx.x * TPB;
  const float* ap0 = tok + (size_t)(T0 + n) * 1024 + kq + kg * 8;
  const float* ap1 = ap0 + 16 * 1024;

  f32x4 acc0 = {0.f, 0.f, 0.f, 0.f}, acc1 = {0.f, 0.f, 0.f, 0.f};

  // ---- 4-slot ring, prefetch depth 3 (12 KB/wave in flight) ----
  f4 r0[4][2], r1[4][2];
#pragma unroll
  for (int s = 0; s < 3; ++s) {
    r0[s][0] = *(const f4*)(ap0 + s * 32);
    r0[s][1] = *(const f4*)(ap0 + s * 32 + 4);
    r1[s][0] = *(const f4*)(ap1 + s * 32);
    r1[s][1] = *(const f4*)(ap1 + s * 32 + 4);
  }

#pragma unroll
  for (int s = 0; s < 8; ++s) {
    const int cs = s & 3, ns = (s + 3) & 3;       // compile-time after unroll
    if (s < 5) {
      r0[ns][0] = *(const f4*)(ap0 + (s + 3) * 32);
      r0[ns][1] = *(const f4*)(ap0 + (s + 3) * 32 + 4);
      r1[ns][0] = *(const f4*)(ap1 + (s + 3) * 32);
      r1[ns][1] = *(const f4*)(ap1 + (s + 3) * 32 + 4);
    }
    s16x8 a0 = pack8(r0[cs][0], r0[cs][1]);
    s16x8 a1 = pack8(r1[cs][0], r1[cs][1]);
    acc0 = __builtin_amdgcn_mfma_f32_16x16x32_bf16(a0, bfrag[s], acc0, 0, 0, 0);
    acc1 = __builtin_amdgcn_mfma_f32_16x16x32_bf16(a1, bfrag[s], acc1, 0, 0, 0);
  }

  // ---- combine 4 k-quarter partials via LDS ----
#pragma unroll
  for (int i = 0; i < 4; ++i) {
    const int row = kg * 4 + i;                    // token-in-tile (R6-verified C layout)
    clds[wv * 512 + row * 16 + n]        = acc0[i];
    clds[wv * 512 + (16 + row) * 16 + n] = acc1[i];
  }
  __syncthreads();

  // ---- 32 parallel softmaxes (threads 0..31, one token each) ----
  if (tid < TPB) {
    float r[9];
#pragma unroll
    for (int j = 0; j < 9; ++j)
      r[j] = (clds[tid * 16 + j] + clds[512 + tid * 16 + j]) +
             (clds[1024 + tid * 16 + j] + clds[1536 + tid * 16 + j]);
    // q=r[0..2], k=r[3..5], v=r[6..8]
    float lg[3];
#pragma unroll
    for (int e = 0; e < 3; ++e) {
      float e0 = __expf(r[e] * r[3]);
      float e1 = __expf(r[e] * r[4]);
      float e2 = __expf(r[e] * r[5]);
      float den = (e0 + e1) + e2;
      float num = e0 * r[6] + e1 * r[7] + e2 * r[8];
      lg[e] = num * __builtin_amdgcn_rcpf(den);
    }
    float u0 = __expf(lg[0]);
    float u1 = __expf(lg[1]);
    float u2 = __expf(lg[2]);
    float rs = __builtin_amdgcn_rcpf((u0 + u1) + u2);
    float* op = out + (size_t)(T0 + tid) * 3;
    op[0] = u0 * rs;
    op[1] = u1 * rs;
    op[2] = u2 * rs;
  }
}

extern "C" void kernel_launch(void* const* d_in, const int* in_sizes, int n_in,
                              void* d_out, int out_size, void* d_ws, size_t ws_size,
                              hipStream_t stream) {
  const float* tok = (const float*)d_in[0];
  const float* Wq  = (const float*)d_in[1];
  const float* Wk  = (const float*)d_in[2];
  const float* Wv  = (const float*)d_in[3];
  float* out = (float*)d_out;

  const int n_tokens = in_sizes[0] / 1024;   // 32768
  const int blocks   = n_tokens / TPB;       // 1024

  hipLaunchKernelGGL(moa_mfma3, dim3(blocks), dim3(256), 0, stream,
                     tok, Wq, Wk, Wv, out);
}